// Round 1
// baseline (423.052 us; speedup 1.0000x reference)
//
#include <hip/hip_runtime.h>

#define N_NODES 50000
#define N_EDGES 800000
#define D 128
#define GEMM_ROWS 16

// ---------------- degree histogram ----------------
__global__ void hist_kernel(const int* __restrict__ dst, int* __restrict__ cnt) {
    int e = blockIdx.x * blockDim.x + threadIdx.x;
    if (e < N_EDGES) {
        atomicAdd(&cnt[dst[e]], 1);
    }
}

// ---------------- exclusive scan (single block) + dis = rsqrt(deg) ----------------
__global__ void scan_kernel(const int* __restrict__ cnt, int* __restrict__ rowstart,
                            float* __restrict__ dis) {
    __shared__ int buf[2][1024];
    int t = threadIdx.x;
    int running = 0;
    for (int base = 0; base < N_NODES; base += 1024) {
        int i = base + t;
        int v = (i < N_NODES) ? cnt[i] : 0;
        buf[0][t] = v;
        __syncthreads();
        int pin = 0;
        for (int off = 1; off < 1024; off <<= 1) {
            int nv = buf[pin][t];
            if (t >= off) nv += buf[pin][t - off];
            buf[pin ^ 1][t] = nv;
            __syncthreads();
            pin ^= 1;
        }
        int incl = buf[pin][t];   // inclusive scan of this tile
        if (i < N_NODES) {
            rowstart[i] = running + incl - v;           // exclusive prefix
            dis[i] = rsqrtf((float)(v + 1));            // +1 self-loop; deg>0 always
        }
        running += buf[pin][1023];                      // tile total (uniform)
        __syncthreads();                                // protect buf before next tile
    }
    if (t == 0) rowstart[N_NODES] = running;
}

// ---------------- scatter edges into CSR ----------------
__global__ void scatter_kernel(const int* __restrict__ src, const int* __restrict__ dst,
                               const int* __restrict__ rowstart, int* __restrict__ cursor,
                               const float* __restrict__ dis,
                               int* __restrict__ col, float* __restrict__ wsrc) {
    int e = blockIdx.x * blockDim.x + threadIdx.x;
    if (e < N_EDGES) {
        int s = src[e], d = dst[e];
        int p = rowstart[d] + atomicAdd(&cursor[d], 1);
        col[p] = s;
        wsrc[p] = dis[s];
    }
}

// ---------------- H = X @ W  (fp32, vector ALU; no fp32 MFMA on CDNA4) ----------------
__global__ __launch_bounds__(256) void gemm_kernel(const float* __restrict__ X,
                                                   const float* __restrict__ W,
                                                   float* __restrict__ H) {
    __shared__ float Xs[GEMM_ROWS * D];
    int t = threadIdx.x;
    int rbase = blockIdx.x * GEMM_ROWS;
    // stage 16 rows of X into LDS (coalesced)
    for (int idx = t; idx < GEMM_ROWS * D; idx += 256)
        Xs[idx] = X[(size_t)rbase * D + idx];
    __syncthreads();
    int c  = t & 127;   // output column
    int rg = t >> 7;    // 0..1, 8 rows each
    float acc[8] = {0.f, 0.f, 0.f, 0.f, 0.f, 0.f, 0.f, 0.f};
    const float* Wc = W + c;            // W[k][c], row-major [K][N]
    const float* Xr = Xs + (rg * 8) * D;
    #pragma unroll 4
    for (int k = 0; k < D; k++) {
        float wv = Wc[k * D];           // coalesced across c; L1/L2-hot
        #pragma unroll
        for (int i = 0; i < 8; i++)
            acc[i] += Xr[i * D + k] * wv;   // LDS broadcast (uniform addr per wave)
    }
    #pragma unroll
    for (int i = 0; i < 8; i++)
        H[(size_t)(rbase + rg * 8 + i) * D + c] = acc[i];
}

// ---------------- per-dst gather-aggregate + bias + ReLU ----------------
__global__ __launch_bounds__(64) void aggr_kernel(const float* __restrict__ Hin,
                                                  const float* __restrict__ dis,
                                                  const int* __restrict__ rowstart,
                                                  const int* __restrict__ col,
                                                  const float* __restrict__ wsrc,
                                                  const float* __restrict__ bias,
                                                  float* __restrict__ Hout) {
    int n = blockIdx.x;
    int t = threadIdx.x;            // 0..63, 2 channels per lane
    const float2* H2 = (const float2*)Hin;
    float disd = dis[n];
    float2 self = H2[(size_t)n * 64 + t];
    float w0 = disd * disd;         // self-loop weight
    float ax = self.x * w0, ay = self.y * w0;
    int beg = rowstart[n], end = rowstart[n + 1];
    for (int p = beg; p < end; p++) {
        int s = col[p];             // uniform per block
        float w = wsrc[p] * disd;   // dis[src]*dis[dst]
        float2 hv = H2[(size_t)s * 64 + t];   // 512B gather per wave
        ax += hv.x * w;
        ay += hv.y * w;
    }
    float2 bb = ((const float2*)bias)[t];
    ax = fmaxf(ax + bb.x, 0.f);
    ay = fmaxf(ay + bb.y, 0.f);
    float2 o; o.x = ax; o.y = ay;
    ((float2*)Hout)[(size_t)n * 64 + t] = o;
}

extern "C" void kernel_launch(void* const* d_in, const int* in_sizes, int n_in,
                              void* d_out, int out_size, void* d_ws, size_t ws_size,
                              hipStream_t stream) {
    const float* x  = (const float*)d_in[0];
    const int*   ei = (const int*)d_in[1];   // harness passes integers as int32
    const float* W1 = (const float*)d_in[2];
    const float* b1 = (const float*)d_in[3];
    const float* W2 = (const float*)d_in[4];
    const float* b2 = (const float*)d_in[5];
    float* out = (float*)d_out;

    char* ws = (char*)d_ws;
    size_t off = 0;
    auto alloc = [&](size_t bytes) -> void* {
        void* p = ws + off;
        off += (bytes + 255) & ~(size_t)255;
        return p;
    };
    int*   cnt      = (int*)alloc((size_t)N_NODES * 4);
    int*   cursor   = (int*)alloc((size_t)N_NODES * 4);
    int*   rowstart = (int*)alloc((size_t)(N_NODES + 1) * 4);
    float* dis      = (float*)alloc((size_t)N_NODES * 4);
    int*   col      = (int*)alloc((size_t)N_EDGES * 4);
    float* wsrc     = (float*)alloc((size_t)N_EDGES * 4);
    float* HA       = (float*)alloc((size_t)N_NODES * D * 4);
    float* HB       = (float*)alloc((size_t)N_NODES * D * 4);

    const int* src = ei;             // edge_index[0]
    const int* dst = ei + N_EDGES;   // edge_index[1]

    // zero cnt + cursor (workspace is poisoned 0xAA before every call)
    hipMemsetAsync(cnt, 0, (size_t)((char*)rowstart - (char*)cnt), stream);

    hist_kernel<<<(N_EDGES + 255) / 256, 256, 0, stream>>>(dst, cnt);
    scan_kernel<<<1, 1024, 0, stream>>>(cnt, rowstart, dis);
    scatter_kernel<<<(N_EDGES + 255) / 256, 256, 0, stream>>>(src, dst, rowstart, cursor,
                                                              dis, col, wsrc);

    gemm_kernel<<<N_NODES / GEMM_ROWS, 256, 0, stream>>>(x, W1, HA);
    aggr_kernel<<<N_NODES, 64, 0, stream>>>(HA, dis, rowstart, col, wsrc, b1, HB);
    gemm_kernel<<<N_NODES / GEMM_ROWS, 256, 0, stream>>>(HB, W2, HA);
    aggr_kernel<<<N_NODES, 64, 0, stream>>>(HA, dis, rowstart, col, wsrc, b2, out);
}